// Round 16
// baseline (60.046 us; speedup 1.0000x reference)
//
#include <hip/hip_runtime.h>

#define RES 1024
#define NV 8
#define HW (RES * RES)

typedef float f32x4 __attribute__((ext_vector_type(4)));
typedef float f32x2 __attribute__((ext_vector_type(2)));

// ---------------------------------------------------------------- bbox partial scan
__global__ __launch_bounds__(256) void bbox_partial(const float* __restrict__ masks,
                                                    int4* __restrict__ part) {
    const int v = blockIdx.y;
    const int b = blockIdx.x;                 // 0..127
    const float4* m = (const float4*)(masks + (size_t)v * HW);
    int lminy = 1 << 30, lmaxy = -1, lminx = 1 << 30, lmaxx = -1;
    int base = b * 2048 + threadIdx.x;
#pragma unroll
    for (int i = 0; i < 8; ++i) {
        int q = base + i * 256;
        float4 f = m[q];
        bool a = f.x > 0.5f, bb = f.y > 0.5f, c = f.z > 0.5f, d = f.w > 0.5f;
        if (a | bb | c | d) {
            int lin = q << 2;
            int y = lin >> 10;
            int x = lin & (RES - 1);
            lminy = min(lminy, y); lmaxy = max(lmaxy, y);
            if (a)  { lminx = min(lminx, x);     lmaxx = max(lmaxx, x);     }
            if (bb) { lminx = min(lminx, x + 1); lmaxx = max(lmaxx, x + 1); }
            if (c)  { lminx = min(lminx, x + 2); lmaxx = max(lmaxx, x + 2); }
            if (d)  { lminx = min(lminx, x + 3); lmaxx = max(lmaxx, x + 3); }
        }
    }
    __shared__ int s[4];
    if (threadIdx.x == 0) { s[0] = 1 << 30; s[1] = -1; s[2] = 1 << 30; s[3] = -1; }
    __syncthreads();
    if (lmaxy >= 0) {
        atomicMin(&s[0], lminy); atomicMax(&s[1], lmaxy);
        atomicMin(&s[2], lminx); atomicMax(&s[3], lmaxx);
    }
    __syncthreads();
    if (threadIdx.x == 0) part[v * 128 + b] = make_int4(s[0], s[1], s[2], s[3]);
}

// ---------------------------------------------------------------- resample + rot90, 4 j-tiles/block
// j-FASTEST grid (page-dense writes, R15's win) + 4 consecutive j-tiles per block
// (512B contiguous per row per block, prologue amortized 4x) + register
// double-buffered load pipeline + LDS double-buffer (one barrier per tile).

#define ISSUE(IT, S)                                                              \
    do {                                                                          \
        _Pragma("unroll")                                                         \
        for (int k = 0; k < 4; ++k) {                                             \
            float ysf = (float)(j0base + 32 * (IT) + ty + 8 * k) - pt;            \
            vv[S][k] = vx & (ysf >= 0.0f) & (ysf < ohf);                          \
            float sy = fmaxf(__fadd_rn(__fmul_rn(__fadd_rn(ysf, 0.5f), syi), -0.5f), 0.0f); \
            float fly = floorf(sy);                                               \
            fy[S][k] = sy - fly;                                                  \
            float y0f = fminf(fmaxf(fly, 0.0f), hn - 1.0f);                       \
            float y1f = fminf(y0f + 1.0f, hn - 1.0f);                             \
            int r0 = ((int)(y0f + mh)) * RES + off;                               \
            int r1 = ((int)(y1f + mh)) * RES + off;                               \
            float nyf = fminf(fmaxf(floorf(__fmul_rn(ysf, syi)), 0.0f), hn - 1.0f); \
            int rn = ((int)(nyf + mh)) * RES + gnx;                               \
            _Pragma("unroll")                                                     \
            for (int p = 0; p < 3; ++p) {                                         \
                __builtin_memcpy(&P0[S][p][k], rgbp[p] + r0, 8);                  \
                __builtin_memcpy(&P1[S][p][k], rgbp[p] + r1, 8);                  \
            }                                                                     \
            MM[S][k] = maskp[rn];                                                 \
        }                                                                         \
    } while (0)

#define COMPUTEWRITE(IT, S)                                                       \
    do {                                                                          \
        _Pragma("unroll")                                                         \
        for (int p = 0; p < 3; ++p) {                                             \
            _Pragma("unroll")                                                     \
            for (int k = 0; k < 4; ++k) {                                         \
                float a = ia ? P0[S][p][k].y : P0[S][p][k].x;                     \
                float b = ib ? P0[S][p][k].y : P0[S][p][k].x;                     \
                float c = ia ? P1[S][p][k].y : P1[S][p][k].x;                     \
                float d = ib ? P1[S][p][k].y : P1[S][p][k].x;                     \
                float top = a * omfx + b * fx;                                    \
                float bot = c * omfx + d * fx;                                    \
                float val = top * (1.0f - fy[S][k]) + bot * fy[S][k];             \
                int r = ty + 8 * k;                                               \
                tile[S][p][r][tx ^ r] = vv[S][k] ? val : 0.0f;                    \
            }                                                                     \
        }                                                                         \
        _Pragma("unroll")                                                         \
        for (int k = 0; k < 4; ++k) {                                             \
            int r = ty + 8 * k;                                                   \
            tile[S][3][r][tx ^ r] = vv[S][k] ? MM[S][k] : 0.0f;                   \
        }                                                                         \
    } while (0)

__global__ __launch_bounds__(256, 2) void resample_kernel(const float* __restrict__ rgbs,
                                                          const float* __restrict__ masks,
                                                          const int4* __restrict__ part,
                                                          const float* __restrict__ kc,
                                                          float* __restrict__ out,
                                                          float* __restrict__ kc_out) {
    const int v = blockIdx.z;
    const int j0base = blockIdx.x * 128;  // 4 j-tiles (output cols)  [FASTEST]
    const int x0b = blockIdx.y * 32;      // S x tile (output rows)
    const int t = threadIdx.x;            // 0..255
    const int tx = t & 31;
    const int ty = t >> 5;
    const int il = t >> 3;
    const int q  = t & 7;
    const int ibase = 992 - x0b;

    __shared__ float Pp[10];
    __shared__ float tile[2][4][32][32];  // double-buffered, XOR-swizzled

    if (t < 64) {
        int4 pa = part[v * 128 + t];
        int4 pb = part[v * 128 + 64 + t];
        int bminh = min(pa.x, pb.x), bmaxh = max(pa.y, pb.y);
        int bminw = min(pa.z, pb.z), bmaxw = max(pa.w, pb.w);
#pragma unroll
        for (int o = 32; o; o >>= 1) {
            bminh = min(bminh, __shfl_down(bminh, o));
            bmaxh = max(bmaxh, __shfl_down(bmaxh, o));
            bminw = min(bminw, __shfl_down(bminw, o));
            bmaxw = max(bmaxw, __shfl_down(bmaxw, o));
        }
        if (t == 0) {
            if (bmaxh < 0) { bminh = 0; bmaxh = RES - 1; }   // empty-mask fallback
            if (bmaxw < 0) { bminw = 0; bmaxw = RES - 1; }
            float mh = (float)min(max(bminh - 100, 0), RES - 1);
            float Mh = (float)min(max(bmaxh + 100, 0), RES - 1);
            float mw = (float)min(max(bminw - 100, 0), RES - 1);
            float Mw = (float)min(max(bmaxw + 100, 0), RES - 1);
            float hn = Mh - mh, wn = Mw - mw;
            bool vert = (hn >= wn);
            float ohf = vert ? 1024.0f : floorf(__fdiv_rn(__fmul_rn(hn, 1024.0f), wn));
            float owf = vert ? floorf(__fdiv_rn(__fmul_rn(wn, 1024.0f), hn)) : 1024.0f;
            float ptp = floorf(__fmul_rn(1024.0f - ohf, 0.5f));
            float plp = floorf(__fmul_rn(1024.0f - owf, 0.5f));
            Pp[0] = mh; Pp[1] = mw; Pp[2] = hn; Pp[3] = wn;
            Pp[4] = ohf; Pp[5] = owf; Pp[6] = ptp; Pp[7] = plp;
            Pp[8] = __fdiv_rn(wn, owf);
            Pp[9] = __fdiv_rn(hn, ohf);
            if (x0b == 0 && j0base == 0) {
                // kc_new = R @ (A @ kc),  R = [[0,1,0],[-1,0,1024],[0,0,1]] (ROT_DEG==1)
                float axk = __fdiv_rn(owf, wn), ayk = __fdiv_rn(ohf, hn);
                float t0 = plp - mw * axk;
                float t1 = ptp - mh * ayk;
                const float* K = kc + v * 9;
                float* O = kc_out + v * 9;
#pragma unroll
                for (int k = 0; k < 3; ++k) {
                    float M0 = axk * K[k]     + t0 * K[6 + k];
                    float M1 = ayk * K[3 + k] + t1 * K[6 + k];
                    float M2 = K[6 + k];
                    O[k]     = M1;
                    O[3 + k] = -M0 + 1024.0f * M2;
                    O[6 + k] = M2;
                }
            }
        }
    }
    __syncthreads();

    const float mh = Pp[0], mw = Pp[1], hn = Pp[2], wn = Pp[3];
    const float ohf = Pp[4], owf = Pp[5], pt = Pp[6], pl = Pp[7];
    const float sxi = Pp[8], syi = Pp[9];

    float* outp[4];
#pragma unroll
    for (int p = 0; p < 3; ++p) outp[p] = out + (size_t)(v * 3 + p) * HW;
    outp[3] = out + (size_t)(NV * 3) * HW + (size_t)v * HW;
    const float* rgbp[3];
#pragma unroll
    for (int p = 0; p < 3; ++p) rgbp[p] = rgbs + (size_t)(v * 3 + p) * HW;
    const float* maskp = masks + (size_t)v * HW;

    // ---- x coords: hoisted, identical for all 4 tiles ----
    float xs = (float)(x0b + tx) - pl;
    bool vx = (xs >= 0.0f) && (xs < owf);
    float sx = fmaxf(__fadd_rn(__fmul_rn(__fadd_rn(xs, 0.5f), sxi), -0.5f), 0.0f);
    float flx = floorf(sx);
    float fx = sx - flx;
    float x0f = fminf(fmaxf(flx, 0.0f), wn - 1.0f);
    float x1f = fminf(x0f + 1.0f, wn - 1.0f);
    int gx0 = (int)(x0f + mw);
    int gx1 = (int)(x1f + mw);
    float nxf = fminf(fmaxf(floorf(__fmul_rn(xs, sxi)), 0.0f), wn - 1.0f);
    int gnx = (int)(nxf + mw);
    const int off = min(gx0, RES - 2);
    const int ia  = gx0 - off;
    const int ib  = gx1 - off;
    const float omfx = 1.0f - fx;
    const int xl = 31 - il;

    const bool xr = ((float)(x0b + 31) >= pl) && ((float)x0b < pl + owf);
    bool av[4];
#pragma unroll
    for (int it = 0; it < 4; ++it) {
        float jlo = (float)(j0base + 32 * it);
        av[it] = xr && ((jlo + 31.0f) >= pt) && (jlo < pt + ohf);
    }

    // per-set state (statically indexed after full unroll)
    float fy[2][4];
    bool  vv[2][4];
    f32x2 P0[2][3][4], P1[2][3][4];
    float MM[2][4];

    if (av[0]) ISSUE(0, 0);

#pragma unroll
    for (int it = 0; it < 4; ++it) {
        const int s = it & 1;
        const int ns = s ^ 1;
        if (it < 3 && av[it + 1]) ISSUE(it + 1, ns);
        if (av[it]) COMPUTEWRITE(it, s);
        __syncthreads();
        const size_t obase = (size_t)(ibase + il) * RES + (j0base + 32 * it) + 4 * q;
        if (av[it]) {
#pragma unroll
            for (int p = 0; p < 4; ++p) {
                f32x4 w;
                w.x = tile[s][p][4 * q + 0][xl ^ (4 * q + 0)];
                w.y = tile[s][p][4 * q + 1][xl ^ (4 * q + 1)];
                w.z = tile[s][p][4 * q + 2][xl ^ (4 * q + 2)];
                w.w = tile[s][p][4 * q + 3][xl ^ (4 * q + 3)];
                *(f32x4*)(outp[p] + obase) = w;
            }
        } else {
            f32x4 z4 = (f32x4)0.0f;
#pragma unroll
            for (int p = 0; p < 4; ++p)
                *(f32x4*)(outp[p] + obase) = z4;
        }
    }
}

extern "C" void kernel_launch(void* const* d_in, const int* in_sizes, int n_in,
                              void* d_out, int out_size, void* d_ws, size_t ws_size,
                              hipStream_t stream) {
    const float* rgbs  = (const float*)d_in[0];
    const float* masks = (const float*)d_in[1];
    const float* kc    = (const float*)d_in[2];
    float* out = (float*)d_out;
    int4* part = (int4*)d_ws;                              // NV*128*16 = 16384 B
    float* kc_out = out + (size_t)NV * 3 * HW + (size_t)NV * HW;   // offset 33554432

    bbox_partial<<<dim3(128, NV), 256, 0, stream>>>(masks, part);
    resample_kernel<<<dim3(8, 32, NV), 256, 0, stream>>>(
        rgbs, masks, part, kc, out, kc_out);
}

// Round 17
// 56.680 us; speedup vs baseline: 1.0594x; 1.0594x over previous
//
#include <hip/hip_runtime.h>

#define RES 1024
#define NV 8
#define HW (RES * RES)

typedef float f32x4 __attribute__((ext_vector_type(4)));
typedef float f32x2 __attribute__((ext_vector_type(2)));

// ---------------------------------------------------------------- bbox partial scan
// 128 blocks per view; each block reduces its 2048-quad chunk into one int4 partial.
__global__ __launch_bounds__(256) void bbox_partial(const float* __restrict__ masks,
                                                    int4* __restrict__ part) {
    const int v = blockIdx.y;
    const int b = blockIdx.x;                 // 0..127
    const float4* m = (const float4*)(masks + (size_t)v * HW);
    int lminy = 1 << 30, lmaxy = -1, lminx = 1 << 30, lmaxx = -1;
    int base = b * 2048 + threadIdx.x;
#pragma unroll
    for (int i = 0; i < 8; ++i) {
        int q = base + i * 256;
        float4 f = m[q];
        bool a = f.x > 0.5f, bb = f.y > 0.5f, c = f.z > 0.5f, d = f.w > 0.5f;
        if (a | bb | c | d) {
            int lin = q << 2;
            int y = lin >> 10;
            int x = lin & (RES - 1);
            lminy = min(lminy, y); lmaxy = max(lmaxy, y);
            if (a)  { lminx = min(lminx, x);     lmaxx = max(lmaxx, x);     }
            if (bb) { lminx = min(lminx, x + 1); lmaxx = max(lmaxx, x + 1); }
            if (c)  { lminx = min(lminx, x + 2); lmaxx = max(lmaxx, x + 2); }
            if (d)  { lminx = min(lminx, x + 3); lmaxx = max(lmaxx, x + 3); }
        }
    }
    __shared__ int s[4];
    if (threadIdx.x == 0) { s[0] = 1 << 30; s[1] = -1; s[2] = 1 << 30; s[3] = -1; }
    __syncthreads();
    if (lmaxy >= 0) {
        atomicMin(&s[0], lminy); atomicMax(&s[1], lmaxy);
        atomicMin(&s[2], lminx); atomicMax(&s[3], lmaxx);
    }
    __syncthreads();
    if (threadIdx.x == 0) part[v * 128 + b] = make_int4(s[0], s[1], s[2], s[3]);
}

// ---------------------------------------------------------------- resample + rot90 (+params prologue)
// R15 structure (j-FASTEST grid -> page-dense writes; batched up-front loads;
// LDS transpose). ONE change vs R15: nontemporal float4 stores, so output
// bypasses L3 and the inputs stay L3-resident across replays.
__global__ __launch_bounds__(256) void resample_kernel(const float* __restrict__ rgbs,
                                                       const float* __restrict__ masks,
                                                       const int4* __restrict__ part,
                                                       const float* __restrict__ kc,
                                                       float* __restrict__ out,
                                                       float* __restrict__ kc_out) {
    const int v = blockIdx.z;
    const int x0b = blockIdx.y * 32;  // source-x tile (output rows)
    const int y0b = blockIdx.x * 32;  // source-y tile (output cols)  [FASTEST]
    const int t = threadIdx.x;        // 0..255
    const int tx = t & 31;            // x within S tile
    const int ty = t >> 5;            // 0..7
    const int il = t >> 3;            // output row within tile (epilogue)
    const int q  = t & 7;             // float4 group (epilogue)
    const int ibase = 992 - x0b;      // RES-1-(x0b+31)

    __shared__ float Pp[10];

    if (t < 64) {
        int4 pa = part[v * 128 + t];
        int4 pb = part[v * 128 + 64 + t];
        int bminh = min(pa.x, pb.x), bmaxh = max(pa.y, pb.y);
        int bminw = min(pa.z, pb.z), bmaxw = max(pa.w, pb.w);
#pragma unroll
        for (int o = 32; o; o >>= 1) {
            bminh = min(bminh, __shfl_down(bminh, o));
            bmaxh = max(bmaxh, __shfl_down(bmaxh, o));
            bminw = min(bminw, __shfl_down(bminw, o));
            bmaxw = max(bmaxw, __shfl_down(bmaxw, o));
        }
        if (t == 0) {
            if (bmaxh < 0) { bminh = 0; bmaxh = RES - 1; }   // empty-mask fallback
            if (bmaxw < 0) { bminw = 0; bmaxw = RES - 1; }
            float mh = (float)min(max(bminh - 100, 0), RES - 1);
            float Mh = (float)min(max(bmaxh + 100, 0), RES - 1);
            float mw = (float)min(max(bminw - 100, 0), RES - 1);
            float Mw = (float)min(max(bmaxw + 100, 0), RES - 1);
            float hn = Mh - mh, wn = Mw - mw;
            bool vert = (hn >= wn);
            float ohf = vert ? 1024.0f : floorf(__fdiv_rn(__fmul_rn(hn, 1024.0f), wn));
            float owf = vert ? floorf(__fdiv_rn(__fmul_rn(wn, 1024.0f), hn)) : 1024.0f;
            float ptp = floorf(__fmul_rn(1024.0f - ohf, 0.5f));
            float plp = floorf(__fmul_rn(1024.0f - owf, 0.5f));
            Pp[0] = mh; Pp[1] = mw; Pp[2] = hn; Pp[3] = wn;
            Pp[4] = ohf; Pp[5] = owf; Pp[6] = ptp; Pp[7] = plp;
            Pp[8] = __fdiv_rn(wn, owf);
            Pp[9] = __fdiv_rn(hn, ohf);
            if (x0b == 0 && y0b == 0) {
                // kc_new = R @ (A @ kc),  R = [[0,1,0],[-1,0,1024],[0,0,1]] (ROT_DEG==1)
                float axk = __fdiv_rn(owf, wn), ayk = __fdiv_rn(ohf, hn);
                float t0 = plp - mw * axk;
                float t1 = ptp - mh * ayk;
                const float* K = kc + v * 9;
                float* O = kc_out + v * 9;
#pragma unroll
                for (int k = 0; k < 3; ++k) {
                    float M0 = axk * K[k]     + t0 * K[6 + k];
                    float M1 = ayk * K[3 + k] + t1 * K[6 + k];
                    float M2 = K[6 + k];
                    O[k]     = M1;
                    O[3 + k] = -M0 + 1024.0f * M2;
                    O[6 + k] = M2;
                }
            }
        }
    }
    __syncthreads();

    const float mh = Pp[0], mw = Pp[1], hn = Pp[2], wn = Pp[3];
    const float ohf = Pp[4], owf = Pp[5], pt = Pp[6], pl = Pp[7];
    const float sxi = Pp[8], syi = Pp[9];

    float* outp[4];
#pragma unroll
    for (int p = 0; p < 3; ++p) outp[p] = out + (size_t)(v * 3 + p) * HW;
    outp[3] = out + (size_t)(NV * 3) * HW + (size_t)v * HW;
    const size_t obase = (size_t)(ibase + il) * RES + y0b + 4 * q;

    // tile-level validity vs valid window [pl, pl+ow) x [pt, pt+oh)
    bool anyv = ((float)(x0b + 31) >= pl) && ((float)x0b < pl + owf) &&
                ((float)(y0b + 31) >= pt) && ((float)y0b < pt + ohf);
    if (!anyv) {
        f32x4 z4 = (f32x4)0.0f;
#pragma unroll
        for (int p = 0; p < 4; ++p)
            __builtin_nontemporal_store(z4, (f32x4*)(outp[p] + obase));
        return;
    }

    // per-thread x (S column) coords
    float xs = (float)(x0b + tx) - pl;
    bool vx = (xs >= 0.0f) && (xs < owf);
    float sx = fmaxf(__fadd_rn(__fmul_rn(__fadd_rn(xs, 0.5f), sxi), -0.5f), 0.0f);
    float flx = floorf(sx);
    float fx = sx - flx;
    float x0f = fminf(fmaxf(flx, 0.0f), wn - 1.0f);
    float x1f = fminf(x0f + 1.0f, wn - 1.0f);
    int gx0 = (int)(x0f + mw);
    int gx1 = (int)(x1f + mw);
    float nxf = fminf(fmaxf(floorf(__fmul_rn(xs, sxi)), 0.0f), wn - 1.0f);
    int gnx = (int)(nxf + mw);

    // paired-load offsets: corners (gx0, gx1) sit in one 8B window at off
    const int off  = min(gx0, RES - 2);
    const int ia   = gx0 - off;            // 0 or 1
    const int ib   = gx1 - off;            // 0 or 1

    // per-thread y (S row) coords, 4 sub-rows
    int ro0[4], ro1[4], ron[4];
    float fy[4];
    bool vyk[4];
#pragma unroll
    for (int k = 0; k < 4; ++k) {
        float ysf = (float)(y0b + ty + 8 * k) - pt;
        vyk[k] = vx & (ysf >= 0.0f) & (ysf < ohf);
        float sy = fmaxf(__fadd_rn(__fmul_rn(__fadd_rn(ysf, 0.5f), syi), -0.5f), 0.0f);
        float fly = floorf(sy);
        fy[k] = sy - fly;
        float y0f = fminf(fmaxf(fly, 0.0f), hn - 1.0f);
        float y1f = fminf(y0f + 1.0f, hn - 1.0f);
        ro0[k] = ((int)(y0f + mh)) * RES + off;
        ro1[k] = ((int)(y1f + mh)) * RES + off;
        float nyf = fminf(fmaxf(floorf(__fmul_rn(ysf, syi)), 0.0f), hn - 1.0f);
        ron[k] = ((int)(nyf + mh)) * RES + gnx;
    }

    // ---- issue ALL 28 loads up-front (addresses are always in-bounds) ----
    f32x2 P0[3][4], P1[3][4];
    float M[4];
#pragma unroll
    for (int p = 0; p < 3; ++p) {
        const float* img = rgbs + (size_t)(v * 3 + p) * HW;
#pragma unroll
        for (int k = 0; k < 4; ++k) {
            __builtin_memcpy(&P0[p][k], img + ro0[k], 8);
            __builtin_memcpy(&P1[p][k], img + ro1[k], 8);
        }
    }
    {
        const float* img = masks + (size_t)v * HW;
#pragma unroll
        for (int k = 0; k < 4; ++k) M[k] = img[ron[k]];
    }

    __shared__ float tile[4][32][33];   // [plane][y_local][x_local]
    const float omfx = 1.0f - fx;

#pragma unroll
    for (int p = 0; p < 3; ++p) {
#pragma unroll
        for (int k = 0; k < 4; ++k) {
            float a = ia ? P0[p][k].y : P0[p][k].x;
            float b = ib ? P0[p][k].y : P0[p][k].x;
            float c = ia ? P1[p][k].y : P1[p][k].x;
            float d = ib ? P1[p][k].y : P1[p][k].x;
            float top = a * omfx + b * fx;
            float bot = c * omfx + d * fx;
            float val = top * (1.0f - fy[k]) + bot * fy[k];
            tile[p][ty + 8 * k][tx] = vyk[k] ? val : 0.0f;
        }
    }
#pragma unroll
    for (int k = 0; k < 4; ++k)
        tile[3][ty + 8 * k][tx] = vyk[k] ? M[k] : 0.0f;

    __syncthreads();

    const int xl = 31 - il;   // S x_local for this output row
#pragma unroll
    for (int p = 0; p < 4; ++p) {
        f32x4 w;
        w.x = tile[p][4 * q + 0][xl];
        w.y = tile[p][4 * q + 1][xl];
        w.z = tile[p][4 * q + 2][xl];
        w.w = tile[p][4 * q + 3][xl];
        __builtin_nontemporal_store(w, (f32x4*)(outp[p] + obase));
    }
}

extern "C" void kernel_launch(void* const* d_in, const int* in_sizes, int n_in,
                              void* d_out, int out_size, void* d_ws, size_t ws_size,
                              hipStream_t stream) {
    const float* rgbs  = (const float*)d_in[0];
    const float* masks = (const float*)d_in[1];
    const float* kc    = (const float*)d_in[2];
    float* out = (float*)d_out;
    int4* part = (int4*)d_ws;                              // NV*128*16 = 16384 B
    float* kc_out = out + (size_t)NV * 3 * HW + (size_t)NV * HW;   // offset 33554432

    bbox_partial<<<dim3(128, NV), 256, 0, stream>>>(masks, part);
    resample_kernel<<<dim3(32, 32, NV), 256, 0, stream>>>(
        rgbs, masks, part, kc, out, kc_out);
}